// Round 1
// baseline (185.185 us; speedup 1.0000x reference)
//
#include <hip/hip_runtime.h>

// PointPillars voxelization, MI355X.
// Grid: 400 x 400 x 1 = 160000 cells. MAX_VOX=60000, MAX_PTS=32, feats=5.
// Outputs (concatenated in d_out as float32 values):
//   voxels [60000,32,5], coords zyx [60000,3], num_points [60000]

constexpr int GXc = 400;
constexpr int GYc = 400;
constexpr int NCELL = GXc * GYc;       // 160000
constexpr int MAXV  = 60000;
constexpr int MAXP  = 32;
constexpr int NF    = 5;

constexpr int SCAN_B = 256;
constexpr int SCAN_E = 8;
constexpr int SCAN_TILE = SCAN_B * SCAN_E;                    // 2048
constexpr int NSCANBLK = (NCELL + SCAN_TILE - 1) / SCAN_TILE; // 79

__device__ __forceinline__ int point_cell(float x, float y, float z) {
    // replicate: floor((p - vmin)/vsize), vsize=(0.25,0.25,8), vmin=(-50,-50,-5)
    int cx = (int)floorf((x + 50.0f) * 4.0f);     // /0.25 exact
    int cy = (int)floorf((y + 50.0f) * 4.0f);
    int cz = (int)floorf((z + 5.0f) * 0.125f);    // /8 exact
    if (cx < 0 || cx >= GXc || cy < 0 || cy >= GYc || cz != 0) return -1;
    return cy * GXc + cx;
}

__global__ void k_count(const float* __restrict__ pts, int N, int* __restrict__ counts) {
    int i = blockIdx.x * blockDim.x + threadIdx.x;
    if (i >= N) return;
    float x = pts[(size_t)i * NF + 0];
    float y = pts[(size_t)i * NF + 1];
    float z = pts[(size_t)i * NF + 2];
    int c = point_cell(x, y, z);
    if (c >= 0) atomicAdd(&counts[c], 1);
}

// Fused scan: low 32 bits = counts (for cellStart), high 32 = occupied flag (for voxIdx).
__global__ void k_scan_local(const int* __restrict__ counts,
                             unsigned long long* __restrict__ excl,
                             unsigned long long* __restrict__ blockSums) {
    __shared__ unsigned long long sh[SCAN_B];
    int base = blockIdx.x * SCAN_TILE;
    unsigned long long vals[SCAN_E];
    unsigned long long sum = 0;
    for (int e = 0; e < SCAN_E; e++) {
        int idx = base + threadIdx.x * SCAN_E + e;
        unsigned long long v = 0;
        if (idx < NCELL) {
            int c = counts[idx];
            v = (unsigned long long)(unsigned)c | ((unsigned long long)(c > 0) << 32);
        }
        vals[e] = sum;
        sum += v;
    }
    sh[threadIdx.x] = sum;
    __syncthreads();
    for (int off = 1; off < SCAN_B; off <<= 1) {
        unsigned long long t = (threadIdx.x >= (unsigned)off) ? sh[threadIdx.x - off] : 0ull;
        __syncthreads();
        sh[threadIdx.x] += t;
        __syncthreads();
    }
    unsigned long long thrExcl = (threadIdx.x == 0) ? 0ull : sh[threadIdx.x - 1];
    for (int e = 0; e < SCAN_E; e++) {
        int idx = base + threadIdx.x * SCAN_E + e;
        if (idx < NCELL) excl[idx] = thrExcl + vals[e];
    }
    if (threadIdx.x == SCAN_B - 1) blockSums[blockIdx.x] = sh[SCAN_B - 1];
}

__global__ void k_scan_blocks(unsigned long long* __restrict__ blockSums, int nb) {
    if (threadIdx.x == 0 && blockIdx.x == 0) {
        unsigned long long run = 0;
        for (int i = 0; i < nb; i++) {
            unsigned long long v = blockSums[i];
            blockSums[i] = run;
            run += v;
        }
    }
}

__global__ void k_scan_final(const unsigned long long* __restrict__ excl,
                             const unsigned long long* __restrict__ blockSums,
                             int* __restrict__ cellStart, int* __restrict__ voxIdx) {
    int c = blockIdx.x * blockDim.x + threadIdx.x;
    if (c >= NCELL) return;
    unsigned long long v = excl[c] + blockSums[c / SCAN_TILE];
    cellStart[c] = (int)(v & 0xffffffffull);
    voxIdx[c]    = (int)(v >> 32);
}

__global__ void k_scatter(const float* __restrict__ pts, int N,
                          const int* __restrict__ cellStart,
                          int* __restrict__ cursor, int* __restrict__ order) {
    int i = blockIdx.x * blockDim.x + threadIdx.x;
    if (i >= N) return;
    float x = pts[(size_t)i * NF + 0];
    float y = pts[(size_t)i * NF + 1];
    float z = pts[(size_t)i * NF + 2];
    int c = point_cell(x, y, z);
    if (c < 0) return;
    int pos = cellStart[c] + atomicAdd(&cursor[c], 1);
    order[pos] = i;
}

__global__ void k_finalize(const float* __restrict__ pts,
                           const int* __restrict__ counts,
                           const int* __restrict__ cellStart,
                           const int* __restrict__ voxIdx,
                           int* __restrict__ order,
                           float* __restrict__ outVox,
                           float* __restrict__ outCoord,
                           float* __restrict__ outNum) {
    int c = blockIdx.x * blockDim.x + threadIdx.x;
    if (c >= NCELL) return;
    int n = counts[c];
    if (n == 0) return;
    int v = voxIdx[c];
    if (v >= MAXV) return;
    int s = cellStart[c];
    // stable order = ascending original point index; insertion sort the segment
    for (int i = 1; i < n; i++) {
        int key = order[s + i];
        int j = i - 1;
        while (j >= 0 && order[s + j] > key) { order[s + j + 1] = order[s + j]; j--; }
        order[s + j + 1] = key;
    }
    int num = n < MAXP ? n : MAXP;
    outNum[v] = (float)num;
    outCoord[(size_t)v * 3 + 0] = 0.0f;                 // cz
    outCoord[(size_t)v * 3 + 1] = (float)(c / GXc);     // cy
    outCoord[(size_t)v * 3 + 2] = (float)(c % GXc);     // cx
    float* dst = outVox + (size_t)v * MAXP * NF;
    for (int r = 0; r < num; r++) {
        int p = order[s + r];
        const float* src = pts + (size_t)p * NF;
        #pragma unroll
        for (int f = 0; f < NF; f++) dst[r * NF + f] = src[f];
    }
}

extern "C" void kernel_launch(void* const* d_in, const int* in_sizes, int n_in,
                              void* d_out, int out_size, void* d_ws, size_t ws_size,
                              hipStream_t stream) {
    const float* pts = (const float*)d_in[0];
    int N = in_sizes[0] / NF;

    float* out      = (float*)d_out;
    float* outVox   = out;                                   // 60000*32*5
    float* outCoord = out + (size_t)MAXV * MAXP * NF;        // 60000*3
    float* outNum   = outCoord + (size_t)MAXV * 3;           // 60000

    // workspace layout (256B aligned chunks)
    char* ws = (char*)d_ws;
    auto take = [&](size_t bytes) {
        char* p = ws;
        ws += (bytes + 255) & ~(size_t)255;
        return p;
    };
    int* counts                    = (int*)take((size_t)NCELL * 4);
    int* cellStart                 = (int*)take((size_t)NCELL * 4);
    int* voxIdx                    = (int*)take((size_t)NCELL * 4);
    int* cursor                    = (int*)take((size_t)NCELL * 4);
    unsigned long long* excl       = (unsigned long long*)take((size_t)NCELL * 8);
    unsigned long long* blockSums  = (unsigned long long*)take((size_t)128 * 8);
    int* order                     = (int*)take((size_t)N * 4);

    hipMemsetAsync(d_out, 0, (size_t)out_size * sizeof(float), stream);
    hipMemsetAsync(counts, 0, (size_t)NCELL * 4, stream);
    hipMemsetAsync(cursor, 0, (size_t)NCELL * 4, stream);

    int nb = (N + 255) / 256;
    k_count<<<nb, 256, 0, stream>>>(pts, N, counts);
    k_scan_local<<<NSCANBLK, SCAN_B, 0, stream>>>(counts, excl, blockSums);
    k_scan_blocks<<<1, 64, 0, stream>>>(blockSums, NSCANBLK);
    k_scan_final<<<(NCELL + 255) / 256, 256, 0, stream>>>(excl, blockSums, cellStart, voxIdx);
    k_scatter<<<nb, 256, 0, stream>>>(pts, N, cellStart, cursor, order);
    k_finalize<<<(NCELL + 255) / 256, 256, 0, stream>>>(pts, counts, cellStart, voxIdx,
                                                        order, outVox, outCoord, outNum);
}

// Round 2
// 154.352 us; speedup vs baseline: 1.1998x; 1.1998x over previous
//
#include <hip/hip_runtime.h>

// PointPillars voxelization, MI355X — round 2.
// Grid: 400 x 400 x 1 = 160000 cells. MAX_VOX=60000, MAX_PTS=32, feats=5.
// d_out (float32): voxels [60000,32,5], coords zyx [60000,3], num_points [60000]
//
// Structure: single scatter pass into per-cell 32-slot arrays -> occupancy-flag
// scan (voxel ids in ascending flat-id order, matching the reference's stable
// argsort) -> wave-per-voxel finalize (parallel rank-sort of <=32 original
// indices, LDS staging, coalesced float4 output incl. zero-fill; no d_out memset).

constexpr int GXc = 400;
constexpr int GYc = 400;
constexpr int NCELL = GXc * GYc;       // 160000
constexpr int MAXV  = 60000;
constexpr int MAXP  = 32;
constexpr int NF    = 5;

constexpr int SCAN_B = 256;
constexpr int SCAN_E = 8;
constexpr int SCAN_TILE = SCAN_B * SCAN_E;                    // 2048
constexpr int NSCANBLK = (NCELL + SCAN_TILE - 1) / SCAN_TILE; // 79

__device__ __forceinline__ int point_cell(float x, float y, float z) {
    // floor((p - vmin)/vsize), vsize=(0.25,0.25,8), vmin=(-50,-50,-5) — exact
    int cx = (int)floorf((x + 50.0f) * 4.0f);
    int cy = (int)floorf((y + 50.0f) * 4.0f);
    int cz = (int)floorf((z + 5.0f) * 0.125f);
    if (cx < 0 || cx >= GXc || cy < 0 || cy >= GYc || cz != 0) return -1;
    return cy * GXc + cx;
}

// One pass over points: count per cell and record first-32 arrivals' indices.
__global__ void k_scatter(const float* __restrict__ pts, int N,
                          int* __restrict__ cursor, int* __restrict__ slots) {
    int i = blockIdx.x * blockDim.x + threadIdx.x;
    if (i >= N) return;
    const float* p = pts + (size_t)i * NF;
    float x = p[0], y = p[1], z = p[2];
    int c = point_cell(x, y, z);
    if (c < 0) return;
    int pos = atomicAdd(&cursor[c], 1);
    if (pos < MAXP) slots[c * MAXP + pos] = i;
}

// Exclusive scan of occupancy flags (cursor[c] > 0) -> per-cell voxel id.
__global__ void k_scan_local(const int* __restrict__ cursor,
                             int* __restrict__ excl, int* __restrict__ blockSums) {
    __shared__ int sh[SCAN_B];
    int base = blockIdx.x * SCAN_TILE;
    int vals[SCAN_E];
    int sum = 0;
    for (int e = 0; e < SCAN_E; e++) {
        int idx = base + threadIdx.x * SCAN_E + e;
        int v = (idx < NCELL && cursor[idx] > 0) ? 1 : 0;
        vals[e] = sum;
        sum += v;
    }
    sh[threadIdx.x] = sum;
    __syncthreads();
    for (int off = 1; off < SCAN_B; off <<= 1) {
        int t = (threadIdx.x >= (unsigned)off) ? sh[threadIdx.x - off] : 0;
        __syncthreads();
        sh[threadIdx.x] += t;
        __syncthreads();
    }
    int thrExcl = (threadIdx.x == 0) ? 0 : sh[threadIdx.x - 1];
    for (int e = 0; e < SCAN_E; e++) {
        int idx = base + threadIdx.x * SCAN_E + e;
        if (idx < NCELL) excl[idx] = thrExcl + vals[e];
    }
    if (threadIdx.x == SCAN_B - 1) blockSums[blockIdx.x] = sh[SCAN_B - 1];
}

__global__ void k_scan_blocks(int* __restrict__ blockSums, int nb,
                              int* __restrict__ nvoxOut) {
    if (threadIdx.x == 0 && blockIdx.x == 0) {
        int run = 0;
        for (int i = 0; i < nb; i++) {
            int v = blockSums[i];
            blockSums[i] = run;
            run += v;
        }
        *nvoxOut = run < MAXV ? run : MAXV;
    }
}

// Finalize voxel ids and build the inverse map voxel -> cell.
__global__ void k_scan_final(const int* __restrict__ cursor,
                             const int* __restrict__ excl,
                             const int* __restrict__ blockSums,
                             int* __restrict__ cellOfVox) {
    int c = blockIdx.x * blockDim.x + threadIdx.x;
    if (c >= NCELL) return;
    if (cursor[c] <= 0) return;
    int v = excl[c] + blockSums[c / SCAN_TILE];
    if (v < MAXV) cellOfVox[v] = c;
}

// One wave per voxel: sort keys by rank, gather points into LDS, write
// coalesced float4s. Tail voxels (v >= nvox) write zeros — no d_out memset.
__global__ void __launch_bounds__(256)
k_finalize(const float* __restrict__ pts,
           const int* __restrict__ cursor,
           const int* __restrict__ slots,
           const int* __restrict__ cellOfVox,
           const int* __restrict__ nvoxPtr,
           float* __restrict__ outVox,
           float* __restrict__ outCoord,
           float* __restrict__ outNum) {
    constexpr int WV = 4;                    // waves per block
    __shared__ float s_dat[WV][MAXP * NF];   // 160 floats per voxel
    __shared__ int   s_key[WV][MAXP];
    __shared__ int   s_srt[WV][MAXP];

    int wv   = threadIdx.x >> 6;
    int lane = threadIdx.x & 63;
    int v    = blockIdx.x * WV + wv;         // grid sized so v < MAXV always
    int nvox = *nvoxPtr;

    int c = 0, num = 0, cnt = 0;
    bool live = (v < nvox);
    if (live) {
        c = cellOfVox[v];
        cnt = cursor[c];
        num = cnt < MAXP ? cnt : MAXP;
    }

    // phase 1: stage keys, zero the data tile
    if (lane < MAXP)
        s_key[wv][lane] = (live && lane < num) ? slots[c * MAXP + lane] : 0x7fffffff;
    #pragma unroll
    for (int k = 0; k < 3; k++) {
        int idx = lane + 64 * k;
        if (idx < MAXP * NF) s_dat[wv][idx] = 0.0f;
    }
    __syncthreads();

    // phase 2: parallel rank sort of the <=32 original indices (all distinct)
    if (lane < MAXP) {
        int key = s_key[wv][lane];
        int rank = 0;
        #pragma unroll
        for (int j = 0; j < MAXP; j++) rank += (s_key[wv][j] < key) ? 1 : 0;
        if (live && lane < num) s_srt[wv][rank] = key;
    }
    __syncthreads();

    // phase 3: gather point rows into LDS (sorted order)
    if (live && lane < num) {
        int p = s_srt[wv][lane];
        const float* src = pts + (size_t)p * NF;
        #pragma unroll
        for (int f = 0; f < NF; f++) s_dat[wv][lane * NF + f] = src[f];
    }
    __syncthreads();

    // phase 4: coalesced output. 160 floats = 40 float4 per voxel.
    const float4* sv = (const float4*)s_dat[wv];
    float4* dst = (float4*)(outVox + (size_t)v * (MAXP * NF));
    if (lane < 40) dst[lane] = sv[lane];
    if (lane == 40) outCoord[(size_t)v * 3 + 0] = 0.0f;
    if (lane == 41) outCoord[(size_t)v * 3 + 1] = live ? (float)(c / GXc) : 0.0f;
    if (lane == 42) outCoord[(size_t)v * 3 + 2] = live ? (float)(c % GXc) : 0.0f;
    if (lane == 43) outNum[v] = live ? (float)num : 0.0f;
}

extern "C" void kernel_launch(void* const* d_in, const int* in_sizes, int n_in,
                              void* d_out, int out_size, void* d_ws, size_t ws_size,
                              hipStream_t stream) {
    const float* pts = (const float*)d_in[0];
    int N = in_sizes[0] / NF;

    float* out      = (float*)d_out;
    float* outVox   = out;
    float* outCoord = out + (size_t)MAXV * MAXP * NF;
    float* outNum   = outCoord + (size_t)MAXV * 3;

    char* ws = (char*)d_ws;
    auto take = [&](size_t bytes) {
        char* p = ws;
        ws += (bytes + 255) & ~(size_t)255;
        return p;
    };
    int* cursor    = (int*)take((size_t)NCELL * 4);
    int* slots     = (int*)take((size_t)NCELL * MAXP * 4);   // 20.5 MB
    int* excl      = (int*)take((size_t)NCELL * 4);
    int* blockSums = (int*)take((size_t)128 * 4);
    int* cellOfVox = (int*)take((size_t)MAXV * 4);
    int* nvoxBuf   = (int*)take(256);

    hipMemsetAsync(cursor, 0, (size_t)NCELL * 4, stream);

    int nb = (N + 255) / 256;
    k_scatter<<<nb, 256, 0, stream>>>(pts, N, cursor, slots);
    k_scan_local<<<NSCANBLK, SCAN_B, 0, stream>>>(cursor, excl, blockSums);
    k_scan_blocks<<<1, 64, 0, stream>>>(blockSums, NSCANBLK, nvoxBuf);
    k_scan_final<<<(NCELL + 255) / 256, 256, 0, stream>>>(cursor, excl, blockSums, cellOfVox);
    k_finalize<<<MAXV / 4, 256, 0, stream>>>(pts, cursor, slots, cellOfVox, nvoxBuf,
                                             outVox, outCoord, outNum);
}

// Round 3
// 145.963 us; speedup vs baseline: 1.2687x; 1.0575x over previous
//
#include <hip/hip_runtime.h>

// PointPillars voxelization, MI355X — round 3.
// Grid: 400 x 400 x 1 = 160000 cells. MAX_VOX=60000, MAX_PTS=32, feats=5.
// d_out (float32): voxels [60000,32,5], coords zyx [60000,3], num_points [60000]
//
// Round-3 changes vs round 2:
//  - k_scatter: 4 points/thread, float4-vectorized loads (5xfloat4 = 80B/thread),
//    4 independent atomicAdd chains per thread (ILP to hide L3-atomic latency).
//  - serial k_scan_blocks kernel REMOVED: k_scanB loads all 79 block sums into
//    LDS and scans them in parallel per block (316B, L2-hot) — the 79-step
//    dependent-global-latency chain (~20us) is gone, one fewer dispatch.
//  - finalize unchanged (wave/voxel, rank-sort, coalesced float4 out, no d_out memset).

constexpr int GXc = 400;
constexpr int GYc = 400;
constexpr int NCELL = GXc * GYc;       // 160000
constexpr int MAXV  = 60000;
constexpr int MAXP  = 32;
constexpr int NF    = 5;

constexpr int SCAN_B = 256;
constexpr int SCAN_E = 8;
constexpr int SCAN_TILE = SCAN_B * SCAN_E;                    // 2048
constexpr int NSCANBLK = (NCELL + SCAN_TILE - 1) / SCAN_TILE; // 79

__device__ __forceinline__ int point_cell(float x, float y, float z) {
    // floor((p - vmin)/vsize), vsize=(0.25,0.25,8), vmin=(-50,-50,-5) — exact
    int cx = (int)floorf((x + 50.0f) * 4.0f);
    int cy = (int)floorf((y + 50.0f) * 4.0f);
    int cz = (int)floorf((z + 5.0f) * 0.125f);
    if (cx < 0 || cx >= GXc || cy < 0 || cy >= GYc || cz != 0) return -1;
    return cy * GXc + cx;
}

// 4 points per thread: 5x float4 vector loads, 4 independent atomic chains.
__global__ void __launch_bounds__(256)
k_scatter(const float* __restrict__ pts, int N,
          int* __restrict__ cursor, int* __restrict__ slots) {
    int t = blockIdx.x * blockDim.x + threadIdx.x;
    int i0 = t * 4;
    if (i0 >= N) return;
    int nrem = N - i0;
    if (nrem >= 4) {
        // 80 bytes = 4 rows of 20B; byte offset 80*t is 16B-aligned.
        const float4* src = (const float4*)(pts + (size_t)i0 * NF);
        float4 q0 = src[0], q1 = src[1], q2 = src[2], q3 = src[3], q4 = src[4];
        float f[20];
        *(float4*)(f + 0)  = q0; *(float4*)(f + 4)  = q1; *(float4*)(f + 8)  = q2;
        *(float4*)(f + 12) = q3; *(float4*)(f + 16) = q4;
        int cs[4];
        #pragma unroll
        for (int k = 0; k < 4; k++)
            cs[k] = point_cell(f[k * 5 + 0], f[k * 5 + 1], f[k * 5 + 2]);
        int pos[4];
        #pragma unroll
        for (int k = 0; k < 4; k++)
            pos[k] = (cs[k] >= 0) ? atomicAdd(&cursor[cs[k]], 1) : 0x7fffffff;
        #pragma unroll
        for (int k = 0; k < 4; k++)
            if (cs[k] >= 0 && pos[k] < MAXP) slots[cs[k] * MAXP + pos[k]] = i0 + k;
    } else {
        for (int k = 0; k < nrem; k++) {
            const float* p = pts + (size_t)(i0 + k) * NF;
            int c = point_cell(p[0], p[1], p[2]);
            if (c >= 0) {
                int pos = atomicAdd(&cursor[c], 1);
                if (pos < MAXP) slots[c * MAXP + pos] = i0 + k;
            }
        }
    }
}

// Per-2048-cell-tile local exclusive scan of occupancy flags.
__global__ void k_scanA(const int* __restrict__ cursor,
                        int* __restrict__ excl, int* __restrict__ blockSums) {
    __shared__ int sh[SCAN_B];
    int base = blockIdx.x * SCAN_TILE;
    int vals[SCAN_E];
    int sum = 0;
    for (int e = 0; e < SCAN_E; e++) {
        int idx = base + threadIdx.x * SCAN_E + e;
        int v = (idx < NCELL && cursor[idx] > 0) ? 1 : 0;
        vals[e] = sum;
        sum += v;
    }
    sh[threadIdx.x] = sum;
    __syncthreads();
    for (int off = 1; off < SCAN_B; off <<= 1) {
        int t = (threadIdx.x >= (unsigned)off) ? sh[threadIdx.x - off] : 0;
        __syncthreads();
        sh[threadIdx.x] += t;
        __syncthreads();
    }
    int thrExcl = (threadIdx.x == 0) ? 0 : sh[threadIdx.x - 1];
    for (int e = 0; e < SCAN_E; e++) {
        int idx = base + threadIdx.x * SCAN_E + e;
        if (idx < NCELL) excl[idx] = thrExcl + vals[e];
    }
    if (threadIdx.x == SCAN_B - 1) blockSums[blockIdx.x] = sh[SCAN_B - 1];
}

// Every block re-scans the 79 block sums in LDS (parallel, L2-hot) and
// builds the voxel->cell inverse map. Block 0 also publishes nvox.
__global__ void k_scanB(const int* __restrict__ cursor,
                        const int* __restrict__ excl,
                        const int* __restrict__ blockSums,
                        int* __restrict__ cellOfVox,
                        int* __restrict__ nvoxOut) {
    __shared__ int sb[128];
    int tid = threadIdx.x;
    if (tid < 128) sb[tid] = (tid < NSCANBLK) ? blockSums[tid] : 0;
    __syncthreads();
    for (int off = 1; off < 128; off <<= 1) {
        int t = (tid < 128 && tid >= off) ? sb[tid - off] : 0;
        __syncthreads();
        if (tid < 128) sb[tid] += t;
        __syncthreads();
    }
    // sb is now inclusive scan of blockSums
    int c = blockIdx.x * blockDim.x + tid;
    if (c < NCELL && cursor[c] > 0) {
        int blk = c / SCAN_TILE;
        int basev = (blk == 0) ? 0 : sb[blk - 1];
        int v = basev + excl[c];
        if (v < MAXV) cellOfVox[v] = c;
    }
    if (blockIdx.x == 0 && tid == 0) {
        int tot = sb[NSCANBLK - 1];
        *nvoxOut = tot < MAXV ? tot : MAXV;
    }
}

// One wave per voxel: parallel rank-sort of <=32 original indices, gather
// rows into LDS, write coalesced float4s. Tail voxels write zeros.
__global__ void __launch_bounds__(256)
k_finalize(const float* __restrict__ pts,
           const int* __restrict__ cursor,
           const int* __restrict__ slots,
           const int* __restrict__ cellOfVox,
           const int* __restrict__ nvoxPtr,
           float* __restrict__ outVox,
           float* __restrict__ outCoord,
           float* __restrict__ outNum) {
    constexpr int WV = 4;                    // waves per block
    __shared__ float s_dat[WV][MAXP * NF];   // 160 floats per voxel
    __shared__ int   s_key[WV][MAXP];
    __shared__ int   s_srt[WV][MAXP];

    int wv   = threadIdx.x >> 6;
    int lane = threadIdx.x & 63;
    int v    = blockIdx.x * WV + wv;         // grid sized so v < MAXV always
    int nvox = *nvoxPtr;

    int c = 0, num = 0, cnt = 0;
    bool live = (v < nvox);
    if (live) {
        c = cellOfVox[v];
        cnt = cursor[c];
        num = cnt < MAXP ? cnt : MAXP;
    }

    if (lane < MAXP)
        s_key[wv][lane] = (live && lane < num) ? slots[c * MAXP + lane] : 0x7fffffff;
    #pragma unroll
    for (int k = 0; k < 3; k++) {
        int idx = lane + 64 * k;
        if (idx < MAXP * NF) s_dat[wv][idx] = 0.0f;
    }
    __syncthreads();

    if (lane < MAXP) {
        int key = s_key[wv][lane];
        int rank = 0;
        #pragma unroll
        for (int j = 0; j < MAXP; j++) rank += (s_key[wv][j] < key) ? 1 : 0;
        if (live && lane < num) s_srt[wv][rank] = key;
    }
    __syncthreads();

    if (live && lane < num) {
        int p = s_srt[wv][lane];
        const float* src = pts + (size_t)p * NF;
        #pragma unroll
        for (int f = 0; f < NF; f++) s_dat[wv][lane * NF + f] = src[f];
    }
    __syncthreads();

    const float4* sv = (const float4*)s_dat[wv];
    float4* dst = (float4*)(outVox + (size_t)v * (MAXP * NF));
    if (lane < 40) dst[lane] = sv[lane];
    if (lane == 40) outCoord[(size_t)v * 3 + 0] = 0.0f;
    if (lane == 41) outCoord[(size_t)v * 3 + 1] = live ? (float)(c / GXc) : 0.0f;
    if (lane == 42) outCoord[(size_t)v * 3 + 2] = live ? (float)(c % GXc) : 0.0f;
    if (lane == 43) outNum[v] = live ? (float)num : 0.0f;
}

extern "C" void kernel_launch(void* const* d_in, const int* in_sizes, int n_in,
                              void* d_out, int out_size, void* d_ws, size_t ws_size,
                              hipStream_t stream) {
    const float* pts = (const float*)d_in[0];
    int N = in_sizes[0] / NF;

    float* out      = (float*)d_out;
    float* outVox   = out;
    float* outCoord = out + (size_t)MAXV * MAXP * NF;
    float* outNum   = outCoord + (size_t)MAXV * 3;

    char* ws = (char*)d_ws;
    auto take = [&](size_t bytes) {
        char* p = ws;
        ws += (bytes + 255) & ~(size_t)255;
        return p;
    };
    int* cursor    = (int*)take((size_t)NCELL * 4);
    int* slots     = (int*)take((size_t)NCELL * MAXP * 4);   // 20.5 MB
    int* excl      = (int*)take((size_t)NCELL * 4);
    int* blockSums = (int*)take((size_t)128 * 4);
    int* cellOfVox = (int*)take((size_t)MAXV * 4);
    int* nvoxBuf   = (int*)take(256);

    hipMemsetAsync(cursor, 0, (size_t)NCELL * 4, stream);

    int nt = (N + 3) / 4;                 // threads for scatter (4 pts each)
    int nb = (nt + 255) / 256;
    k_scatter<<<nb, 256, 0, stream>>>(pts, N, cursor, slots);
    k_scanA<<<NSCANBLK, SCAN_B, 0, stream>>>(cursor, excl, blockSums);
    k_scanB<<<(NCELL + 255) / 256, 256, 0, stream>>>(cursor, excl, blockSums,
                                                     cellOfVox, nvoxBuf);
    k_finalize<<<MAXV / 4, 256, 0, stream>>>(pts, cursor, slots, cellOfVox, nvoxBuf,
                                             outVox, outCoord, outNum);
}